// Round 3
// baseline (996.929 us; speedup 1.0000x reference)
//
#include <hip/hip_runtime.h>

typedef float f4 __attribute__((ext_vector_type(4)));

#define NB   1024   // batch
#define TT   256    // seq len
#define EE   100    // embed dim
#define GG1  256    // 4*H1
#define GG2  128    // 4*H2
#define KC2  96     // layer-2 combined k-depth (64 + 32)
#define RPB  2      // rows per block
#define NTHR 512

__device__ __forceinline__ float fast_sigmoid(float x) {
  return __builtin_amdgcn_rcpf(1.0f + __expf(-x));
}
__device__ __forceinline__ float fast_tanh(float x) {
  return 1.0f - 2.0f * __builtin_amdgcn_rcpf(1.0f + __expf(2.0f * x));
}

__global__ __launch_bounds__(NTHR, 4) void lstm_fused(
    const int* __restrict__ tokens, const float* __restrict__ emb,
    const float* __restrict__ W1, const float* __restrict__ U1, const float* __restrict__ b1,
    const float* __restrict__ W2, const float* __restrict__ U2, const float* __restrict__ b2,
    const float* __restrict__ Wd, const float* __restrict__ bd,
    float* __restrict__ out)
{
  __shared__ float sWC[KC2][GG2];        // 48 KB: rows 0..63 = W2, 64..95 = U2
  __shared__ f4    sX[RPB][EE / 4];      // single-buffered (write window is bar1..bar2)
  __shared__ f4    sHH[RPB][24];         // f4 0..15 = h1 (64 fl), 16..23 = h2 (32 fl)
  __shared__ float sZ1[RPB][GG1];
  __shared__ float sZ2[RPB][GG2];
  __shared__ int   sTok[RPB][TT];

  const int tid  = threadIdx.x;
  const int s    = tid & 1;        // k-half
  const int j    = tid >> 1;       // layer-1 gate column 0..255
  const int c    = j & (GG2 - 1);  // layer-2 gate column 0..127
  const int r2   = tid >> 8;       // layer-2 row 0/1
  const int row0 = blockIdx.x * RPB;

  // ---- layer-1 weights into registers (k-split across lane pairs) ----
  f4 wA[13];  // W1 half: s=0 -> k in [0,50), s=1 -> k in [50,100)
  #pragma unroll
  for (int qq = 0; qq < 13; ++qq) {
    #pragma unroll
    for (int kk = 0; kk < 4; ++kk) {
      int k = 48 * s + 4 * qq + kk;
      bool own = s ? (k >= 50) : (k < 50);
      wA[qq][kk] = own ? W1[k * GG1 + j] : 0.0f;
    }
  }
  f4 uB[8];   // U1 half: k in [32s, 32s+32)
  #pragma unroll
  for (int qq = 0; qq < 8; ++qq) {
    #pragma unroll
    for (int kk = 0; kk < 4; ++kk) {
      int k = 32 * s + 4 * qq + kk;
      uB[qq][kk] = U1[k * GG1 + j];
    }
  }
  const float bb1 = b1[j];
  const float bb2 = b2[c];
  const int   gc1 = j >> 6;   // 0:i 1:f 2:g 3:o (wave-uniform)
  const int   gc2 = c >> 5;

  // ---- one-time LDS init ----
  #pragma unroll
  for (int it = 0; it < (KC2 * GG2) / NTHR; ++it) {   // 24 iters, coalesced
    int idx = tid + it * NTHR;
    int k = idx >> 7, cc = idx & (GG2 - 1);
    ((float*)sWC)[idx] = (k < 64) ? W2[k * GG2 + cc] : U2[(k - 64) * GG2 + cc];
  }
  {
    int idx = tid;                                    // RPB*TT = 512 tokens
    int r = idx >> 8, t = idx & (TT - 1);
    sTok[r][t] = tokens[(size_t)(row0 + r) * TT + t];
  }
  if (tid < RPB * 24 * 4) ((float*)sHH)[tid] = 0.0f;
  float c1 = 0.0f;   // L1 cell: thread tid<128 owns (r=tid>>6, u=tid&63)
  float c2 = 0.0f;   // L2 cell: thread tid<64  owns (r=tid>>5, u=tid&31)
  __syncthreads();

  // ---- prologue: x(t=0) ----
  {
    int pr = -1, pq = 0;
    if (tid >= 256 && tid < 256 + 25)      { pr = 0; pq = tid - 256; }
    else if (tid >= 384 && tid < 384 + 25) { pr = 1; pq = tid - 384; }
    if (pr >= 0) sX[pr][pq] = ((const f4*)(emb + (size_t)sTok[pr][0] * EE))[pq];
  }
  __syncthreads();

  for (int t = 0; t < TT; ++t) {
    // ---- A: issue prefetch of x(t+1) (waves 4 and 6; one 16B load each) ----
    f4 pf; int pr = -1, pq = 0;
    if (t + 1 < TT) {
      if (tid >= 256 && tid < 256 + 25)      { pr = 0; pq = tid - 256; }
      else if (tid >= 384 && tid < 384 + 25) { pr = 1; pq = tid - 384; }
      if (pr >= 0) pf = ((const f4*)(emb + (size_t)sTok[pr][t + 1] * EE))[pq];
    }

    // ---- B: layer-1 gate partials (all 512 threads) ----
    float a0 = 0.f, a1 = 0.f;
    #pragma unroll
    for (int qq = 0; qq < 13; ++qq) {            // x @ W1 (half)
      int q = 12 * s + qq;
      f4 x0 = sX[0][q], x1 = sX[1][q];
      #pragma unroll
      for (int kk = 0; kk < 4; ++kk) {
        float w = wA[qq][kk];
        a0 = fmaf(x0[kk], w, a0); a1 = fmaf(x1[kk], w, a1);
      }
    }
    #pragma unroll
    for (int qq = 0; qq < 8; ++qq) {             // h1 @ U1 (half)
      int q = 8 * s + qq;
      f4 h0 = sHH[0][q], h1 = sHH[1][q];
      #pragma unroll
      for (int kk = 0; kk < 4; ++kk) {
        float w = uB[qq][kk];
        a0 = fmaf(h0[kk], w, a0); a1 = fmaf(h1[kk], w, a1);
      }
    }
    a0 += __shfl_xor(a0, 1); a1 += __shfl_xor(a1, 1);
    if (s == 0) {
      float z0 = a0 + bb1, z1 = a1 + bb1;
      if (gc1 == 2) { z0 = fast_tanh(z0); z1 = fast_tanh(z1); }
      else          { z0 = fast_sigmoid(z0); z1 = fast_sigmoid(z1); }
      sZ1[0][j] = z0; sZ1[1][j] = z1;
    }
    __syncthreads();                             // bar1: sZ1 ready, sX reads done

    // ---- C: layer-1 state update (128 thr) | prefetch write (waves 4/6) ----
    if (tid < 128) {
      int r = tid >> 6, u = tid & 63;
      bool m = (sTok[r][t] != 0);
      float iv = sZ1[r][u], fv = sZ1[r][64 + u], gv = sZ1[r][128 + u], ov = sZ1[r][192 + u];
      float cn = fv * c1 + iv * gv;
      float hn = ov * fast_tanh(cn);
      if (m) { c1 = cn; ((float*)&sHH[r][0])[u] = hn; }
    } else if (pr >= 0) {
      sX[pr][pq] = pf;
    }
    __syncthreads();                             // bar2: h1 + next x ready

    // ---- D: layer-2 gate partials (all 512 threads; weights from LDS) ----
    {
      float g = 0.f;
      #pragma unroll
      for (int qq = 0; qq < 12; ++qq) {
        int q = 12 * s + qq;                     // kcomb = 4q+kk in [48s, 48s+48)
        f4 hv = sHH[r2][q];
        g = fmaf(hv[0], sWC[4 * q + 0][c], g);
        g = fmaf(hv[1], sWC[4 * q + 1][c], g);
        g = fmaf(hv[2], sWC[4 * q + 2][c], g);
        g = fmaf(hv[3], sWC[4 * q + 3][c], g);
      }
      g += __shfl_xor(g, 1);
      if (s == 0) {
        float z = g + bb2;
        z = (gc2 == 2) ? fast_tanh(z) : fast_sigmoid(z);
        sZ2[r2][c] = z;
      }
    }
    __syncthreads();                             // bar3: sZ2 ready

    // ---- E: layer-2 state update (64 thr); hazards covered by bar1/bar2 of t+1 ----
    if (tid < 64) {
      int r = tid >> 5, u = tid & 31;
      bool m = (sTok[r][t] != 0);
      float iv = sZ2[r][u], fv = sZ2[r][32 + u], gv = sZ2[r][64 + u], ov = sZ2[r][96 + u];
      float cn = fv * c2 + iv * gv;
      float hn = ov * fast_tanh(cn);
      if (m) { c2 = cn; ((float*)&sHH[r][0])[64 + u] = hn; }
    }
  }
  __syncthreads();

  // ---- epilogue: out = sigmoid(h2 @ Wd + bd) ----
  if (tid < RPB * 4) {
    int r = tid >> 2, o = tid & 3;
    float a = bd[o];
    #pragma unroll
    for (int u = 0; u < 32; ++u)
      a = fmaf(((float*)&sHH[r][0])[64 + u], Wd[u * 4 + o], a);
    out[(size_t)(row0 + r) * 4 + o] = fast_sigmoid(a);
  }
}

extern "C" void kernel_launch(void* const* d_in, const int* in_sizes, int n_in,
                              void* d_out, int out_size, void* d_ws, size_t ws_size,
                              hipStream_t stream) {
  const int*   tokens = (const int*)d_in[0];
  const float* emb    = (const float*)d_in[1];
  const float* W1     = (const float*)d_in[2];
  const float* U1     = (const float*)d_in[3];
  const float* b1     = (const float*)d_in[4];
  const float* W2     = (const float*)d_in[5];
  const float* U2     = (const float*)d_in[6];
  const float* b2     = (const float*)d_in[7];
  const float* Wd     = (const float*)d_in[8];
  const float* bd     = (const float*)d_in[9];
  float* out = (float*)d_out;

  lstm_fused<<<dim3(NB / RPB), dim3(NTHR), 0, stream>>>(
      tokens, emb, W1, U1, b1, W2, U2, b2, Wd, bd, out);
}

// Round 4
// 521.408 us; speedup vs baseline: 1.9120x; 1.9120x over previous
//
#include <hip/hip_runtime.h>

typedef float f4 __attribute__((ext_vector_type(4)));
typedef float f2 __attribute__((ext_vector_type(2)));

#define NB    1024
#define TT    256
#define EE    100
#define VOCAB 5000
#define GG1   256   // 4*H1
#define GG2   128   // 4*H2
#define RPB   2
#define NTHR  512

__device__ __forceinline__ float fast_sigmoid(float x) {
  return __builtin_amdgcn_rcpf(1.0f + __expf(-x));
}
__device__ __forceinline__ float fast_tanh(float x) {
  return 1.0f - 2.0f * __builtin_amdgcn_rcpf(1.0f + __expf(2.0f * x));
}

// ---- K1: emb_z[v][j] = b1[j] + sum_k emb[v][k] * W1[k][j]  (5000x256) ----
__global__ __launch_bounds__(256) void emb_gemm(
    const float* __restrict__ emb, const float* __restrict__ W1,
    const float* __restrict__ b1, float* __restrict__ emb_z)
{
  __shared__ float sE[8][EE];
  const int j  = threadIdx.x;
  const int v0 = blockIdx.x * 8;
  for (int idx = j; idx < 8 * EE; idx += 256) {
    int r = idx / EE, k = idx % EE;
    sE[r][k] = emb[(size_t)(v0 + r) * EE + k];
  }
  __syncthreads();
  float acc[8];
  const float bb = b1[j];
  #pragma unroll
  for (int r = 0; r < 8; ++r) acc[r] = bb;
  for (int k = 0; k < EE; ++k) {
    float w = W1[k * GG1 + j];
    #pragma unroll
    for (int r = 0; r < 8; ++r) acc[r] = fmaf(sE[r][k], w, acc[r]);
  }
  #pragma unroll
  for (int r = 0; r < 8; ++r) emb_z[(size_t)(v0 + r) * GG1 + j] = acc[r];
}

// ---- K2: persistent 2-layer LSTM scan ----
// B-phase (L1, z += h1@U1): s = tid&3 (k-quarter), j2 = tid>>2 -> cols {2j2, 2j2+1}
// D-phase (L2, [h1;h2]@[W2;U2]): s2 = tid&7, r2 = (tid>>3)&1, j3 = tid>>4 -> cols {4j3..4j3+3}
__global__ __launch_bounds__(NTHR, 4) void lstm_fused(
    const int* __restrict__ tokens, const float* __restrict__ emb_z,
    const float* __restrict__ U1,
    const float* __restrict__ W2, const float* __restrict__ U2, const float* __restrict__ b2,
    const float* __restrict__ Wd, const float* __restrict__ bd,
    float* __restrict__ out)
{
  __shared__ f4    sHH[RPB][24];        // f4 0..15 = h1 (64 fl), 16..23 = h2 (32 fl)
  __shared__ float sZ1[RPB][GG1];
  __shared__ float sZ2[RPB][GG2];
  __shared__ int   sTok[RPB][TT];

  const int tid  = threadIdx.x;
  const int row0 = blockIdx.x * RPB;

  // B-phase decode
  const int s  = tid & 3;
  const int j2 = tid >> 2;              // 0..127 -> cols {2j2, 2j2+1}
  // D-phase decode
  const int s2 = tid & 7;
  const int r2 = (tid >> 3) & 1;
  const int j3 = tid >> 4;              // 0..31  -> cols {4j3..4j3+3}

  // ---- weights into registers ----
  f2 wB[16];   // U1[k][2j2 .. 2j2+1], k = 16*s + kk2
  #pragma unroll
  for (int kk = 0; kk < 16; ++kk)
    wB[kk] = *(const f2*)&U1[(16 * s + kk) * GG1 + 2 * j2];
  f4 wD[12];   // [W2;U2][k][4j3..4j3+3], k = 12*s2 + kk
  #pragma unroll
  for (int kk = 0; kk < 12; ++kk) {
    int k = 12 * s2 + kk;
    wD[kk] = (k < 64) ? *(const f4*)&W2[k * GG2 + 4 * j3]
                      : *(const f4*)&U2[(k - 64) * GG2 + 4 * j3];
  }
  const f4  bD  = *(const f4*)&b2[4 * j3];
  const int gc1 = j2 >> 5;              // gate class for cols {2j2,2j2+1}
  const int gc2 = j3 >> 3;              // gate class for cols {4j3..}

  // ---- one-time LDS init ----
  {
    int r = tid >> 8, t = tid & (TT - 1);
    sTok[r][t] = tokens[(size_t)(row0 + r) * TT + t];
  }
  if (tid < RPB * 96) ((float*)sHH)[tid] = 0.0f;
  float c1 = 0.0f;   // L1 cell: tid<128 owns (r=tid>>6, u=tid&63)
  float c2 = 0.0f;   // L2 cell: tid<64  owns (r=tid>>5, u=tid&31)
  __syncthreads();

  // ---- prefetch z_x(t=0): s==0 lanes load f2 per row ----
  f2 pf0 = {0.f, 0.f}, pf1 = {0.f, 0.f};
  if (s == 0) {
    pf0 = *(const f2*)&emb_z[(size_t)sTok[0][0] * GG1 + 2 * j2];
    pf1 = *(const f2*)&emb_z[(size_t)sTok[1][0] * GG1 + 2 * j2];
  }

  for (int t = 0; t < TT; ++t) {
    // ---- B: L1 gates: z = z_x + h1@U1 ----
    float a0x = 0.f, a0y = 0.f, a1x = 0.f, a1y = 0.f;
    #pragma unroll
    for (int qq = 0; qq < 4; ++qq) {
      f4 h0 = sHH[0][4 * s + qq];
      f4 h1 = sHH[1][4 * s + qq];
      #pragma unroll
      for (int kk = 0; kk < 4; ++kk) {
        f2 w = wB[4 * qq + kk];
        a0x = fmaf(h0[kk], w[0], a0x); a0y = fmaf(h0[kk], w[1], a0y);
        a1x = fmaf(h1[kk], w[0], a1x); a1y = fmaf(h1[kk], w[1], a1y);
      }
    }
    a0x += __shfl_xor(a0x, 1); a0y += __shfl_xor(a0y, 1);
    a1x += __shfl_xor(a1x, 1); a1y += __shfl_xor(a1y, 1);
    a0x += __shfl_xor(a0x, 2); a0y += __shfl_xor(a0y, 2);
    a1x += __shfl_xor(a1x, 2); a1y += __shfl_xor(a1y, 2);
    if (s == 0) {
      float z0x = a0x + pf0[0], z0y = a0y + pf0[1];
      float z1x = a1x + pf1[0], z1y = a1y + pf1[1];
      if (gc1 == 2) { z0x = fast_tanh(z0x); z0y = fast_tanh(z0y);
                      z1x = fast_tanh(z1x); z1y = fast_tanh(z1y); }
      else          { z0x = fast_sigmoid(z0x); z0y = fast_sigmoid(z0y);
                      z1x = fast_sigmoid(z1x); z1y = fast_sigmoid(z1y); }
      f2 o0; o0[0] = z0x; o0[1] = z0y;
      f2 o1; o1[0] = z1x; o1[1] = z1y;
      ((f2*)&sZ1[0][0])[j2] = o0;
      ((f2*)&sZ1[1][0])[j2] = o1;
    }
    __syncthreads();                            // bar1: sZ1 ready, h1 reads done

    // ---- C: L1 state update (tid<128) + z_x(t+1) prefetch (s==0 lanes) ----
    if (t + 1 < TT && s == 0) {
      pf0 = *(const f2*)&emb_z[(size_t)sTok[0][t + 1] * GG1 + 2 * j2];
      pf1 = *(const f2*)&emb_z[(size_t)sTok[1][t + 1] * GG1 + 2 * j2];
    }
    if (tid < 128) {
      int r = tid >> 6, u = tid & 63;
      bool m = (sTok[r][t] != 0);
      float iv = sZ1[r][u], fv = sZ1[r][64 + u], gv = sZ1[r][128 + u], ov = sZ1[r][192 + u];
      float cn = fv * c1 + iv * gv;
      float hn = ov * fast_tanh(cn);
      if (m) { c1 = cn; ((float*)&sHH[r][0])[u] = hn; }
    }
    __syncthreads();                            // bar2: h1 ready

    // ---- D: L2 gates: [h1;h2] @ [W2;U2] ----
    {
      float g0 = 0.f, g1 = 0.f, g2 = 0.f, g3 = 0.f;
      #pragma unroll
      for (int qq = 0; qq < 3; ++qq) {
        f4 hv = sHH[r2][3 * s2 + qq];
        #pragma unroll
        for (int kk = 0; kk < 4; ++kk) {
          f4 w = wD[3 * qq + kk];
          g0 = fmaf(hv[kk], w[0], g0); g1 = fmaf(hv[kk], w[1], g1);
          g2 = fmaf(hv[kk], w[2], g2); g3 = fmaf(hv[kk], w[3], g3);
        }
      }
      g0 += __shfl_xor(g0, 1); g1 += __shfl_xor(g1, 1); g2 += __shfl_xor(g2, 1); g3 += __shfl_xor(g3, 1);
      g0 += __shfl_xor(g0, 2); g1 += __shfl_xor(g1, 2); g2 += __shfl_xor(g2, 2); g3 += __shfl_xor(g3, 2);
      g0 += __shfl_xor(g0, 4); g1 += __shfl_xor(g1, 4); g2 += __shfl_xor(g2, 4); g3 += __shfl_xor(g3, 4);
      if (s2 == 0) {
        float z0 = g0 + bD[0], z1 = g1 + bD[1], z2 = g2 + bD[2], z3 = g3 + bD[3];
        if (gc2 == 2) { z0 = fast_tanh(z0); z1 = fast_tanh(z1);
                        z2 = fast_tanh(z2); z3 = fast_tanh(z3); }
        else          { z0 = fast_sigmoid(z0); z1 = fast_sigmoid(z1);
                        z2 = fast_sigmoid(z2); z3 = fast_sigmoid(z3); }
        f4 o; o[0] = z0; o[1] = z1; o[2] = z2; o[3] = z3;
        ((f4*)&sZ2[r2][0])[j3] = o;
      }
    }
    __syncthreads();                            // bar3: sZ2 ready

    // ---- E: L2 state update (tid<64); hazards covered by bar1/bar2 of t+1 ----
    if (tid < 64) {
      int r = tid >> 5, u = tid & 31;
      bool m = (sTok[r][t] != 0);
      float iv = sZ2[r][u], fv = sZ2[r][32 + u], gv = sZ2[r][64 + u], ov = sZ2[r][96 + u];
      float cn = fv * c2 + iv * gv;
      float hn = ov * fast_tanh(cn);
      if (m) { c2 = cn; ((float*)&sHH[r][0])[64 + u] = hn; }
    }
  }
  __syncthreads();

  // ---- epilogue: out = sigmoid(h2 @ Wd + bd) ----
  if (tid < RPB * 4) {
    int r = tid >> 2, o = tid & 3;
    float a = bd[o];
    #pragma unroll
    for (int u = 0; u < 32; ++u)
      a = fmaf(((float*)&sHH[r][0])[64 + u], Wd[u * 4 + o], a);
    out[(size_t)(row0 + r) * 4 + o] = fast_sigmoid(a);
  }
}

extern "C" void kernel_launch(void* const* d_in, const int* in_sizes, int n_in,
                              void* d_out, int out_size, void* d_ws, size_t ws_size,
                              hipStream_t stream) {
  const int*   tokens = (const int*)d_in[0];
  const float* emb    = (const float*)d_in[1];
  const float* W1     = (const float*)d_in[2];
  const float* U1     = (const float*)d_in[3];
  const float* b1     = (const float*)d_in[4];
  const float* W2     = (const float*)d_in[5];
  const float* U2     = (const float*)d_in[6];
  const float* b2     = (const float*)d_in[7];
  const float* Wd     = (const float*)d_in[8];
  const float* bd     = (const float*)d_in[9];
  float* out   = (float*)d_out;
  float* emb_z = (float*)d_ws;          // 5000*256*4 = 5.12 MB scratch

  emb_gemm<<<dim3(VOCAB / 8), dim3(256), 0, stream>>>(emb, W1, b1, emb_z);
  lstm_fused<<<dim3(NB / RPB), dim3(NTHR), 0, stream>>>(
      tokens, emb_z, U1, W2, U2, b2, Wd, bd, out);
}